// Round 2
// baseline (677.201 us; speedup 1.0000x reference)
//
#include <hip/hip_runtime.h>
#include <math.h>

// Problem constants: B=16, T=4096, D=512, N=9, K=1024, d=8
#define ROWS   65536

// ---- workspace float offsets (total ~699 KB) ----
#define WS_WPAD 0          // W_in_all padded [512][96]: col cc=8i+c at (cc/9)*12+cc%9
#define WS_WOUT 49152      // W_out_all [72][512], row jr = 8j+a
#define WS_CBT  86016      // normalized codebooks transposed [9][8][1024]
#define WS_SC   159744     // sum(cb_n^2) [9][1024]
#define WS_M    168960     // M[j][i][a*8+b] = sum_t Wout[j][a][t]*Win[i][t][b]
#define WS_CACC 174144     // [9][8]: sum_{j<i} out_b_j @ W_in_i
#define WS_SOB  174216     // [512]: sum_j out_b_j
#define WS_LOSS 174728     // double accumulator (8B aligned)

// ---- output float offsets ----
#define OUT_CODES 33554432
#define OUT_LAT   34144256
#define OUT_CLOSS 38862848
#define OUT_CBLOSS 38862849

__device__ __forceinline__ int pcol(int cc){ return (cc/9)*12 + (cc%9); }

// ---------------- prep1: weight-norm + codebook normalize ----------------
__global__ __launch_bounds__(256) void prep1(const float* __restrict__ in_v,
    const float* __restrict__ in_g, const float* __restrict__ out_v,
    const float* __restrict__ out_g, const float* __restrict__ out_b,
    const float* __restrict__ cb, float* __restrict__ ws)
{
    int t = blockIdx.x*256 + threadIdx.x;
    if (t < 9216) {
        // codebook normalize: (i,k)
        int i = t >> 10, k = t & 1023;
        const float* p = cb + (i*1024 + k)*8;
        float v[8]; float ssq = 0.f;
        #pragma unroll
        for (int c=0;c<8;c++){ v[c]=p[c]; ssq = fmaf(v[c],v[c],ssq); }
        float den = fmaxf(sqrtf(ssq), 1e-12f);
        float sc = 0.f;
        #pragma unroll
        for (int c=0;c<8;c++){ float cn = v[c]/den; ws[WS_CBT + (i*8+c)*1024 + k] = cn; sc = fmaf(cn,cn,sc); }
        ws[WS_SC + i*1024 + k] = sc;
    } else if (t < 13824) {
        // W_out: (j, t) norm over a-axis
        int r = t - 9216; int j = r >> 9, tt = r & 511;
        float v[8]; float ssq = 0.f;
        #pragma unroll
        for (int a=0;a<8;a++){ v[a]=out_v[(j*8+a)*512+tt]; ssq=fmaf(v[a],v[a],ssq); }
        float den = fmaxf(sqrtf(ssq), 1e-12f);
        float g = out_g[j*512+tt];
        #pragma unroll
        for (int a=0;a<8;a++) ws[WS_WOUT + (j*8+a)*512 + tt] = g*v[a]/den;
    } else if (t < 18432) {
        // W_in: one wave per (i,c) column, norm over 512 rows (range 64-aligned)
        int r = t - 13824;
        int w = r >> 6, l = r & 63;
        int i = w >> 3, c = w & 7;
        float v[8]; float ssq = 0.f;
        #pragma unroll
        for (int u=0;u<8;u++){ v[u] = in_v[(i*512 + l*8+u)*8 + c]; ssq = fmaf(v[u],v[u],ssq); }
        #pragma unroll
        for (int off=1; off<64; off<<=1) ssq += __shfl_xor(ssq, off, 64);
        float den = fmaxf(sqrtf(ssq), 1e-12f);
        float g = in_g[i*8+c];
        int pc = pcol(i*8+c);
        #pragma unroll
        for (int u=0;u<8;u++) ws[WS_WPAD + (l*8+u)*96 + pc] = g*v[u]/den;
    } else if (t < 18944) {
        int tt = t - 18432;
        float s = 0.f;
        for (int j=0;j<9;j++) s += out_b[j*512+tt];
        ws[WS_SOB + tt] = s;
    } else if (t == 18944) {
        *(double*)&ws[WS_LOSS] = 0.0;
    }
}

// ---------------- prep2: cross-term tables M and Cacc (8 lanes per output) ----
__global__ __launch_bounds__(256) void prep2(const float* __restrict__ out_b,
                                             float* __restrict__ ws)
{
    int g = blockIdx.x*256 + threadIdx.x;
    if (g < 41472) {
        int oi = g >> 3, part = g & 7;
        int j = oi / 576; int rem = oi % 576; int i = rem >> 6; int ab = rem & 63;
        int a = ab >> 3, b = ab & 7;
        int pc = pcol(i*8+b);
        const float* wo = ws + WS_WOUT + (j*8+a)*512 + part*64;
        const float* wp = ws + WS_WPAD + (part*64)*96 + pc;
        float s = 0.f;
        #pragma unroll
        for (int u=0; u<16; u++) {
            float4 w4 = *(const float4*)(wo + u*4);
            s = fmaf(w4.x, wp[(u*4+0)*96], s);
            s = fmaf(w4.y, wp[(u*4+1)*96], s);
            s = fmaf(w4.z, wp[(u*4+2)*96], s);
            s = fmaf(w4.w, wp[(u*4+3)*96], s);
        }
        #pragma unroll
        for (int off=1; off<8; off<<=1) s += __shfl_xor(s, off, 64);
        if (part == 0) ws[WS_M + oi] = s;   // oi == (j*9+i)*64 + ab
    } else if (g < 42048) {
        int r = g - 41472;
        int oi = r >> 3, part = r & 7;
        int i = oi >> 3, b = oi & 7;
        int pc = pcol(i*8+b);
        float s = 0.f;
        for (int u=0; u<64; u++) {
            int tt = part*64 + u;
            float bb = 0.f;
            for (int j=0;j<i;j++) bb += out_b[j*512+tt];
            s = fmaf(bb, ws[WS_WPAD + tt*96+pc], s);
        }
        #pragma unroll
        for (int off=1; off<8; off<<=1) s += __shfl_xor(s, off, 64);
        if (part == 0) ws[WS_CACC + oi] = s;
    }
}

// ---------------- gemm_in: P = z @ W_in_all + in_b  -> latents region ----------------
__global__ __launch_bounds__(256) void gemm_in(const float* __restrict__ z,
    const float* __restrict__ in_b, const float* __restrict__ ws, float* __restrict__ out)
{
    __shared__ float AsT[32*132];   // [k][row], pad 132 keeps b128 aligned
    __shared__ float Bs[32*96];     // [k][padded col groups of 12]
    int tid = threadIdx.x;
    int rowbase = blockIdx.x * 128;
    int tr = tid & 31, tc = tid >> 5;   // thread: rows tr*4..+3, cols tc*9..+8
    float acc[4][9];
    #pragma unroll
    for (int r=0;r<4;r++){
        #pragma unroll
        for(int c=0;c<9;c++) acc[r][c]=0.f;
    }
    int kq = tid & 7, rr = tid >> 3;
    for (int kk=0; kk<16; kk++) {
        #pragma unroll
        for (int p=0;p<4;p++){
            int row = rr + p*32;
            float4 a = *(const float4*)(z + (size_t)(rowbase+row)*512 + kk*32 + kq*4);
            AsT[(kq*4+0)*132 + row] = a.x;
            AsT[(kq*4+1)*132 + row] = a.y;
            AsT[(kq*4+2)*132 + row] = a.z;
            AsT[(kq*4+3)*132 + row] = a.w;
        }
        #pragma unroll
        for (int p=0;p<3;p++){
            int idx = p*256 + tid;
            *(float4*)(Bs + idx*4) = *(const float4*)(ws + WS_WPAD + kk*32*96 + idx*4);
        }
        __syncthreads();
        #pragma unroll 4
        for (int k=0;k<32;k++){
            float4 a  = *(const float4*)(AsT + k*132 + tr*4);
            float4 b0 = *(const float4*)(Bs + k*96 + tc*12);
            float4 b1 = *(const float4*)(Bs + k*96 + tc*12 + 4);
            float  b8 = Bs[k*96 + tc*12 + 8];
            float av[4] = {a.x,a.y,a.z,a.w};
            float bv[9] = {b0.x,b0.y,b0.z,b0.w,b1.x,b1.y,b1.z,b1.w,b8};
            #pragma unroll
            for (int r=0;r<4;r++){
                #pragma unroll
                for (int c=0;c<9;c++) acc[r][c] = fmaf(av[r], bv[c], acc[r][c]);
            }
        }
        __syncthreads();
    }
    #pragma unroll
    for (int c=0;c<9;c++){
        int cc = tc*9+c;
        float bias = in_b[cc];
        #pragma unroll
        for (int r=0;r<4;r++){
            int row = rowbase + tr*4 + r;
            out[OUT_LAT + (size_t)row*72 + cc] = acc[r][c] + bias;
        }
    }
}

// ---------------- step_all: all 9 quantizer stages fused, 512-thread blocks ----------------
// 512 blocks x 512 threads -> 2 blocks/CU x 8 waves = 16 waves/CU (2x prev occupancy).
// Block owns 128 rows. Thread: oct=tid&7 (128-code octant), rowslot=tid>>3 (0..63),
// handles 2 rows (rowslot, rowslot+64). Octant stagger 132 -> conflict-free broadcast.
// dist argmax: t = dot - 0.5*sc, with -0.5*sc folded into the accumulator init.
__global__ __launch_bounds__(512, 4) void step_all(
    const float* __restrict__ cbooks, float* __restrict__ ws, float* __restrict__ out)
{
    __shared__ float lds_cb[8*1056];     // [c][oct][132]
    __shared__ float lds_sc[8*132];      // halved sc, [oct][132]
    __shared__ float codes_lds[128*13];  // [row_in_block][stride 13]
    __shared__ float warr[8];

    int tid = threadIdx.x;
    int oct = tid & 7;
    int rowslot = tid >> 3;              // 0..63
    int rowbase = blockIdx.x * 128;
    const int kbase = oct*128;
    const float* cbo = lds_cb + oct*132;
    const float* sco = lds_sc + oct*132;

    float lacc = 0.f;

    for (int i=0; i<9; i++){
        __syncthreads();   // previous stage's LDS reads done
        // ---- stage cb_i (8192 floats) and halved sc_i (1024 floats) ----
        #pragma unroll
        for (int p=0;p<4;p++){
            int s = (p*512 + tid)*4;
            int c = s >> 10; int k = s & 1023; int o = k >> 7; int kk = k & 127;
            float4 v = *(const float4*)(ws + WS_CBT + i*8192 + s);
            *(float4*)(lds_cb + c*1056 + o*132 + kk) = v;
        }
        if (tid < 256){
            int s = tid*4;
            int o = s >> 7; int kk = s & 127;
            float4 v = *(const float4*)(ws + WS_SC + i*1024 + s);
            v.x *= 0.5f; v.y *= 0.5f; v.z *= 0.5f; v.w *= 0.5f;
            *(float4*)(lds_sc + o*132 + kk) = v;
        }
        __syncthreads();

        // ---- Phase A: z_e per row, normalize; oct0 writes latents ----
        float zen[2][8];
        #pragma unroll
        for (int r=0;r<2;r++){
            int rib = r*64 + rowslot;
            int row = rowbase + rib;
            float* lat = out + OUT_LAT + (size_t)row*72 + i*8;
            float4 p0 = *(const float4*)(lat);
            float4 p1 = *(const float4*)(lat+4);
            float ze[8] = {p0.x,p0.y,p0.z,p0.w,p1.x,p1.y,p1.z,p1.w};
            #pragma unroll
            for (int b=0;b<8;b++) ze[b] -= ws[WS_CACC + i*8 + b];
            for (int j=0;j<i;j++){
                int kj = (int)codes_lds[rib*13 + j];
                const float* qp = cbooks + (size_t)(j*1024+kj)*8;
                float4 q0 = *(const float4*)(qp);
                float4 q1 = *(const float4*)(qp+4);
                float qa[8] = {q0.x,q0.y,q0.z,q0.w,q1.x,q1.y,q1.z,q1.w};
                const float* M = ws + WS_M + (j*9+i)*64;
                #pragma unroll
                for (int a=0;a<8;a++){
                    #pragma unroll
                    for (int b=0;b<8;b++) ze[b] = fmaf(-qa[a], M[a*8+b], ze[b]);
                }
            }
            float ssq = 0.f;
            #pragma unroll
            for (int c=0;c<8;c++) ssq = fmaf(ze[c],ze[c],ssq);
            float den = fmaxf(sqrtf(ssq), 1e-12f);
            float rden = 1.0f/den;
            if (oct == 0){
                float4 z0 = {ze[0],ze[1],ze[2],ze[3]};
                float4 z1 = {ze[4],ze[5],ze[6],ze[7]};
                *(float4*)(lat)   = z0;
                *(float4*)(lat+4) = z1;
            }
            #pragma unroll
            for (int c=0;c<8;c++) zen[r][c] = ze[c]*rden;
        }

        // ---- Phase B: octant distance scan, 2 rows share each LDS chunk ----
        float bv[2]; int bk[2];
        #pragma unroll
        for (int r=0;r<2;r++){ bv[r] = -3.0e38f; bk[r] = kbase; }
        #pragma unroll 2
        for (int kk=0; kk<128; kk+=4){
            float4 v[8];
            #pragma unroll
            for (int c=0;c<8;c++) v[c] = *(const float4*)(cbo + c*1056 + kk);
            float4 hs = *(const float4*)(sco + kk);
            #pragma unroll
            for (int r=0;r<2;r++){
                float d0=-hs.x, d1=-hs.y, d2=-hs.z, d3=-hs.w;
                #pragma unroll
                for (int c=0;c<8;c++){
                    d0 = fmaf(zen[r][c], v[c].x, d0);
                    d1 = fmaf(zen[r][c], v[c].y, d1);
                    d2 = fmaf(zen[r][c], v[c].z, d2);
                    d3 = fmaf(zen[r][c], v[c].w, d3);
                }
                bool c0 = d0 > bv[r]; bk[r] = c0?(kbase+kk+0):bk[r]; bv[r] = c0?d0:bv[r];
                bool c1 = d1 > bv[r]; bk[r] = c1?(kbase+kk+1):bk[r]; bv[r] = c1?d1:bv[r];
                bool c2 = d2 > bv[r]; bk[r] = c2?(kbase+kk+2):bk[r]; bv[r] = c2?d2:bv[r];
                bool c3 = d3 > bv[r]; bk[r] = c3?(kbase+kk+3):bk[r]; bv[r] = c3?d3:bv[r];
            }
        }

        // ---- Phase C: combine 8 octants (ties -> smaller k), outputs, loss ----
        #pragma unroll
        for (int off=1; off<8; off<<=1){
            #pragma unroll
            for (int r=0;r<2;r++){
                float ov = __shfl_xor(bv[r], off, 64);
                int   ok = __shfl_xor(bk[r], off, 64);
                bool rep = (ov > bv[r]) || (ov == bv[r] && ok < bk[r]);
                bv[r] = rep ? ov : bv[r];
                bk[r] = rep ? ok : bk[r];
            }
        }
        if (oct == 0){
            #pragma unroll
            for (int r=0;r<2;r++){
                int rib = r*64 + rowslot;
                int row = rowbase + rib;
                out[OUT_CODES + (size_t)row*9 + i] = (float)bk[r];
                codes_lds[rib*13 + i] = (float)bk[r];
                const float* lat = out + OUT_LAT + (size_t)row*72 + i*8;
                const float* qp = cbooks + (size_t)(i*1024+bk[r])*8;
                float4 z0 = *(const float4*)(lat);
                float4 z1 = *(const float4*)(lat+4);
                float4 q0 = *(const float4*)(qp);
                float4 q1 = *(const float4*)(qp+4);
                float e0 = z0.x-q0.x, e1 = z0.y-q0.y, e2 = z0.z-q0.z, e3 = z0.w-q0.w;
                float e4 = z1.x-q1.x, e5 = z1.y-q1.y, e6 = z1.z-q1.z, e7 = z1.w-q1.w;
                lacc = fmaf(e0,e0,lacc); lacc = fmaf(e1,e1,lacc);
                lacc = fmaf(e2,e2,lacc); lacc = fmaf(e3,e3,lacc);
                lacc = fmaf(e4,e4,lacc); lacc = fmaf(e5,e5,lacc);
                lacc = fmaf(e6,e6,lacc); lacc = fmaf(e7,e7,lacc);
            }
        }
    }

    // ---- loss reduction: one atomic per block ----
    #pragma unroll
    for (int off=1; off<64; off<<=1) lacc += __shfl_xor(lacc, off, 64);
    if ((tid & 63)==0) warr[tid>>6] = lacc;
    __syncthreads();
    if (tid==0){
        double bs = 0.0;
        #pragma unroll
        for (int w=0; w<8; w++) bs += (double)warr[w];
        atomicAdd((double*)&ws[WS_LOSS], bs);
    }
}

// ---------------- gemm_out: z_q = Q @ W_out_all + sum_out_b ----------------
// 512 blocks x 256 threads, 128 rows/block, thread tile 8x8. Q staged TRANSPOSED
// (QLT[k][row]) so A-operand is one b128. Both QLT and Ws rows carry a +4-word
// shift per 8-element group: the 16 stride-32B b128 reads then cover all 8
// float4 bank-slots twice (2-way = free) instead of 4 slots 4x.
__global__ __launch_bounds__(256) void gemm_out(const float* __restrict__ cbooks,
    const float* __restrict__ ws, float* __restrict__ out)
{
    __shared__ float QLT[72*140];   // word = k*140 + row + (row>>5)*4   (max 139)
    __shared__ float Ws[72*140];    // word = k*140 + col + (col>>3)*4   (max 139)
    int tid = threadIdx.x;
    int rowbase = blockIdx.x*128;
    if (tid < 128){
        int row = rowbase + tid;
        int rsw = tid + (tid>>5)*4;
        for (int j=0;j<9;j++){
            int kj = (int)out[OUT_CODES + (size_t)row*9 + j];
            const float* qp = cbooks + (size_t)(j*1024+kj)*8;
            float4 q0 = *(const float4*)qp;
            float4 q1 = *(const float4*)(qp+4);
            QLT[(j*8+0)*140 + rsw] = q0.x;
            QLT[(j*8+1)*140 + rsw] = q0.y;
            QLT[(j*8+2)*140 + rsw] = q0.z;
            QLT[(j*8+3)*140 + rsw] = q0.w;
            QLT[(j*8+4)*140 + rsw] = q1.x;
            QLT[(j*8+5)*140 + rsw] = q1.y;
            QLT[(j*8+6)*140 + rsw] = q1.z;
            QLT[(j*8+7)*140 + rsw] = q1.w;
        }
    }
    int tc = tid & 15, tr = tid >> 4;    // rows tr*8..+7, cols tc*8..+7 per chunk
    int aoff = tr*8 + (tr>>2)*4;
    int boff = tc*8 + (tc>>2)*4;
    for (int cc=0; cc<4; cc++){
        __syncthreads();
        #pragma unroll
        for (int p=0;p<9;p++){
            int idx = p*256 + tid;
            int jr = idx >> 5; int cq = idx & 31;
            float4 w = *(const float4*)(ws + WS_WOUT + jr*512 + cc*128 + cq*4);
            *(float4*)(Ws + jr*140 + cq*4 + (cq>>3)*4) = w;
        }
        __syncthreads();
        float acc[8][8];
        #pragma unroll
        for (int r=0;r<8;r++){
            #pragma unroll
            for (int c=0;c<8;c++) acc[r][c]=0.f;
        }
        #pragma unroll 2
        for (int k=0;k<72;k++){
            float4 a0 = *(const float4*)(QLT + k*140 + aoff);
            float4 a1 = *(const float4*)(QLT + k*140 + aoff + 4);
            float4 b0 = *(const float4*)(Ws + k*140 + boff);
            float4 b1 = *(const float4*)(Ws + k*140 + boff + 4);
            float av[8] = {a0.x,a0.y,a0.z,a0.w,a1.x,a1.y,a1.z,a1.w};
            float bw[8] = {b0.x,b0.y,b0.z,b0.w,b1.x,b1.y,b1.z,b1.w};
            #pragma unroll
            for (int r=0;r<8;r++){
                #pragma unroll
                for (int c=0;c<8;c++) acc[r][c] = fmaf(av[r], bw[c], acc[r][c]);
            }
        }
        float4 s0 = *(const float4*)(ws + WS_SOB + cc*128 + tc*8);
        float4 s1 = *(const float4*)(ws + WS_SOB + cc*128 + tc*8 + 4);
        #pragma unroll
        for (int r=0;r<8;r++){
            int row = rowbase + tr*8 + r;
            float4 o0 = {acc[r][0]+s0.x, acc[r][1]+s0.y, acc[r][2]+s0.z, acc[r][3]+s0.w};
            float4 o1 = {acc[r][4]+s1.x, acc[r][5]+s1.y, acc[r][6]+s1.z, acc[r][7]+s1.w};
            *(float4*)(out + (size_t)row*512 + cc*128 + tc*8)     = o0;
            *(float4*)(out + (size_t)row*512 + cc*128 + tc*8 + 4) = o1;
        }
    }
    if (blockIdx.x==0 && tid==0){
        double L = *(const double*)(ws + WS_LOSS);
        float lv = (float)(L * (1.0/524288.0));   // / (B*T*d)
        out[OUT_CLOSS]  = lv;
        out[OUT_CBLOSS] = lv;
    }
}

extern "C" void kernel_launch(void* const* d_in, const int* in_sizes, int n_in,
                              void* d_out, int out_size, void* d_ws, size_t ws_size,
                              hipStream_t stream) {
    const float* z     = (const float*)d_in[0];
    const float* in_v  = (const float*)d_in[1];
    const float* in_g  = (const float*)d_in[2];
    const float* in_b  = (const float*)d_in[3];
    const float* out_v = (const float*)d_in[4];
    const float* out_g = (const float*)d_in[5];
    const float* out_b = (const float*)d_in[6];
    const float* cb    = (const float*)d_in[7];
    float* out = (float*)d_out;
    float* ws  = (float*)d_ws;

    prep1<<<75, 256, 0, stream>>>(in_v, in_g, out_v, out_g, out_b, cb, ws);
    prep2<<<165, 256, 0, stream>>>(out_b, ws);
    gemm_in<<<512, 256, 0, stream>>>(z, in_b, ws, out);
    step_all<<<512, 512, 0, stream>>>(cb, ws, out);
    gemm_out<<<512, 256, 0, stream>>>(cb, ws, out);
}

// Round 3
// 598.731 us; speedup vs baseline: 1.1311x; 1.1311x over previous
//
#include <hip/hip_runtime.h>
#include <math.h>

// Problem constants: B=16, T=4096, D=512, N=9, K=1024, d=8
#define ROWS   65536

// ---- workspace float offsets (total ~699 KB) ----
#define WS_WPAD 0          // W_in_all padded [512][96]: col cc=8i+c at (cc/9)*12+cc%9
#define WS_WOUT 49152      // W_out_all [72][512], row jr = 8j+a
#define WS_CBT  86016      // normalized codebooks transposed [9][8][1024]
#define WS_SC   159744     // sum(cb_n^2) [9][1024]
#define WS_M    168960     // M[j][i][a*8+b] = sum_t Wout[j][a][t]*Win[i][t][b]
#define WS_CACC 174144     // [9][8]: sum_{j<i} out_b_j @ W_in_i
#define WS_SOB  174216     // [512]: sum_j out_b_j
#define WS_LOSS 174728     // double accumulator (8B aligned)

// ---- output float offsets ----
#define OUT_CODES 33554432
#define OUT_LAT   34144256
#define OUT_CLOSS 38862848
#define OUT_CBLOSS 38862849

__device__ __forceinline__ int pcol(int cc){ return (cc/9)*12 + (cc%9); }

// ---------------- prep1: weight-norm + codebook normalize ----------------
__global__ __launch_bounds__(256) void prep1(const float* __restrict__ in_v,
    const float* __restrict__ in_g, const float* __restrict__ out_v,
    const float* __restrict__ out_g, const float* __restrict__ out_b,
    const float* __restrict__ cb, float* __restrict__ ws)
{
    int t = blockIdx.x*256 + threadIdx.x;
    if (t < 9216) {
        // codebook normalize: (i,k)
        int i = t >> 10, k = t & 1023;
        const float* p = cb + (i*1024 + k)*8;
        float v[8]; float ssq = 0.f;
        #pragma unroll
        for (int c=0;c<8;c++){ v[c]=p[c]; ssq = fmaf(v[c],v[c],ssq); }
        float den = fmaxf(sqrtf(ssq), 1e-12f);
        float sc = 0.f;
        #pragma unroll
        for (int c=0;c<8;c++){ float cn = v[c]/den; ws[WS_CBT + (i*8+c)*1024 + k] = cn; sc = fmaf(cn,cn,sc); }
        ws[WS_SC + i*1024 + k] = sc;
    } else if (t < 13824) {
        // W_out: (j, t) norm over a-axis
        int r = t - 9216; int j = r >> 9, tt = r & 511;
        float v[8]; float ssq = 0.f;
        #pragma unroll
        for (int a=0;a<8;a++){ v[a]=out_v[(j*8+a)*512+tt]; ssq=fmaf(v[a],v[a],ssq); }
        float den = fmaxf(sqrtf(ssq), 1e-12f);
        float g = out_g[j*512+tt];
        #pragma unroll
        for (int a=0;a<8;a++) ws[WS_WOUT + (j*8+a)*512 + tt] = g*v[a]/den;
    } else if (t < 18432) {
        // W_in: one wave per (i,c) column, norm over 512 rows (range 64-aligned)
        int r = t - 13824;
        int w = r >> 6, l = r & 63;
        int i = w >> 3, c = w & 7;
        float v[8]; float ssq = 0.f;
        #pragma unroll
        for (int u=0;u<8;u++){ v[u] = in_v[(i*512 + l*8+u)*8 + c]; ssq = fmaf(v[u],v[u],ssq); }
        #pragma unroll
        for (int off=1; off<64; off<<=1) ssq += __shfl_xor(ssq, off, 64);
        float den = fmaxf(sqrtf(ssq), 1e-12f);
        float g = in_g[i*8+c];
        int pc = pcol(i*8+c);
        #pragma unroll
        for (int u=0;u<8;u++) ws[WS_WPAD + (l*8+u)*96 + pc] = g*v[u]/den;
    } else if (t < 18944) {
        int tt = t - 18432;
        float s = 0.f;
        for (int j=0;j<9;j++) s += out_b[j*512+tt];
        ws[WS_SOB + tt] = s;
    } else if (t == 18944) {
        *(double*)&ws[WS_LOSS] = 0.0;
    }
}

// ---------------- prep2: cross-term tables M and Cacc (8 lanes per output) ----
__global__ __launch_bounds__(256) void prep2(const float* __restrict__ out_b,
                                             float* __restrict__ ws)
{
    int g = blockIdx.x*256 + threadIdx.x;
    if (g < 41472) {
        int oi = g >> 3, part = g & 7;
        int j = oi / 576; int rem = oi % 576; int i = rem >> 6; int ab = rem & 63;
        int a = ab >> 3, b = ab & 7;
        int pc = pcol(i*8+b);
        const float* wo = ws + WS_WOUT + (j*8+a)*512 + part*64;
        const float* wp = ws + WS_WPAD + (part*64)*96 + pc;
        float s = 0.f;
        #pragma unroll
        for (int u=0; u<16; u++) {
            float4 w4 = *(const float4*)(wo + u*4);
            s = fmaf(w4.x, wp[(u*4+0)*96], s);
            s = fmaf(w4.y, wp[(u*4+1)*96], s);
            s = fmaf(w4.z, wp[(u*4+2)*96], s);
            s = fmaf(w4.w, wp[(u*4+3)*96], s);
        }
        #pragma unroll
        for (int off=1; off<8; off<<=1) s += __shfl_xor(s, off, 64);
        if (part == 0) ws[WS_M + oi] = s;   // oi == (j*9+i)*64 + ab
    } else if (g < 42048) {
        int r = g - 41472;
        int oi = r >> 3, part = r & 7;
        int i = oi >> 3, b = oi & 7;
        int pc = pcol(i*8+b);
        float s = 0.f;
        for (int u=0; u<64; u++) {
            int tt = part*64 + u;
            float bb = 0.f;
            for (int j=0;j<i;j++) bb += out_b[j*512+tt];
            s = fmaf(bb, ws[WS_WPAD + tt*96+pc], s);
        }
        #pragma unroll
        for (int off=1; off<8; off<<=1) s += __shfl_xor(s, off, 64);
        if (part == 0) ws[WS_CACC + oi] = s;
    }
}

// ---------------- gemm_in: P = z @ W_in_all + in_b  -> latents region ----------------
__global__ __launch_bounds__(256) void gemm_in(const float* __restrict__ z,
    const float* __restrict__ in_b, const float* __restrict__ ws, float* __restrict__ out)
{
    __shared__ float AsT[32*132];   // [k][row], pad 132 keeps b128 aligned
    __shared__ float Bs[32*96];     // [k][padded col groups of 12]
    int tid = threadIdx.x;
    int rowbase = blockIdx.x * 128;
    int tr = tid & 31, tc = tid >> 5;   // thread: rows tr*4..+3, cols tc*9..+8
    float acc[4][9];
    #pragma unroll
    for (int r=0;r<4;r++){
        #pragma unroll
        for(int c=0;c<9;c++) acc[r][c]=0.f;
    }
    int kq = tid & 7, rr = tid >> 3;
    for (int kk=0; kk<16; kk++) {
        #pragma unroll
        for (int p=0;p<4;p++){
            int row = rr + p*32;
            float4 a = *(const float4*)(z + (size_t)(rowbase+row)*512 + kk*32 + kq*4);
            AsT[(kq*4+0)*132 + row] = a.x;
            AsT[(kq*4+1)*132 + row] = a.y;
            AsT[(kq*4+2)*132 + row] = a.z;
            AsT[(kq*4+3)*132 + row] = a.w;
        }
        #pragma unroll
        for (int p=0;p<3;p++){
            int idx = p*256 + tid;
            *(float4*)(Bs + idx*4) = *(const float4*)(ws + WS_WPAD + kk*32*96 + idx*4);
        }
        __syncthreads();
        #pragma unroll 4
        for (int k=0;k<32;k++){
            float4 a  = *(const float4*)(AsT + k*132 + tr*4);
            float4 b0 = *(const float4*)(Bs + k*96 + tc*12);
            float4 b1 = *(const float4*)(Bs + k*96 + tc*12 + 4);
            float  b8 = Bs[k*96 + tc*12 + 8];
            float av[4] = {a.x,a.y,a.z,a.w};
            float bv[9] = {b0.x,b0.y,b0.z,b0.w,b1.x,b1.y,b1.z,b1.w,b8};
            #pragma unroll
            for (int r=0;r<4;r++){
                #pragma unroll
                for (int c=0;c<9;c++) acc[r][c] = fmaf(av[r], bv[c], acc[r][c]);
            }
        }
        __syncthreads();
    }
    #pragma unroll
    for (int c=0;c<9;c++){
        int cc = tc*9+c;
        float bias = in_b[cc];
        #pragma unroll
        for (int r=0;r<4;r++){
            int row = rowbase + tr*4 + r;
            out[OUT_LAT + (size_t)row*72 + cc] = acc[r][c] + bias;
        }
    }
}

// ---------------- step_all: codes-in-registers, wave-autonomous ----------------
// 512 blocks x 256 threads (4 waves). Wave owns 32 rows end-to-end; NO barriers
// in the stage loop. Each lane holds 16 codes (cb 128 VGPR + prescaled -0.5*sc)
// reloaded per stage from L2; the wave scans one row at a time: phase-B LDS
// traffic is 2 broadcast ds_read_b128 (zen) per row instead of 9 b128/4-codes.
// Phase A: lane pair (2 lanes/row) computes ze redundantly in the exact old
// summation order (bit-identical dists -> identical codes/tie-breaks).
// Argmax: per-lane first-occurrence scan (k = lane*16+rel increasing), wave
// fmax butterfly, ballot+ffs lowest lane (=lowest k) -> exact semantics.
__global__ __launch_bounds__(256, 2) void step_all(
    const float* __restrict__ cbooks, float* __restrict__ ws, float* __restrict__ out)
{
    __shared__ __align__(16) float zen_lds[4*32*12];  // [wave][row][12] (stride 48B)
    __shared__ float codes_lds[128*13];               // [row_in_block][stride 13]
    __shared__ float warr[4];

    int tid = threadIdx.x;
    int w  = tid >> 6;
    int l  = tid & 63;
    int rowhalf = l >> 1;       // row owned by this lane pair (phase A / epilogue)
    int ah = l & 1;
    int rowbase = blockIdx.x*128 + w*32;
    int kb = l*16;              // this lane's code base
    float* zen_w = zen_lds + w*384;

    float lacc = 0.f;

    float4 cbr[4][8];   // [quad][dim] codes kb+4q..+3 at dim c
    float4 hs4[4];      // -0.5*sc for the 4 quads

    #pragma unroll 1
    for (int i=0; i<9; i++){
        // ---- reload this lane's 16 codes + prescaled -0.5*sc (L2-resident) ----
        #pragma unroll
        for (int q=0;q<4;q++){
            #pragma unroll
            for (int c=0;c<8;c++)
                cbr[q][c] = *(const float4*)(ws + WS_CBT + i*8192 + c*1024 + kb + q*4);
            float4 s = *(const float4*)(ws + WS_SC + i*1024 + kb + q*4);
            hs4[q].x = s.x * -0.5f; hs4[q].y = s.y * -0.5f;
            hs4[q].z = s.z * -0.5f; hs4[q].w = s.w * -0.5f;
        }

        // ---- Phase A: ze for own row (pair-redundant, exact old op order) ----
        int row = rowbase + rowhalf;
        int rib = w*32 + rowhalf;
        float* lat = out + OUT_LAT + (size_t)row*72 + i*8;
        float4 p0 = *(const float4*)(lat);
        float4 p1 = *(const float4*)(lat+4);
        float ze[8] = {p0.x,p0.y,p0.z,p0.w,p1.x,p1.y,p1.z,p1.w};
        #pragma unroll
        for (int b=0;b<8;b++) ze[b] -= ws[WS_CACC + i*8 + b];
        #pragma unroll 1
        for (int j=0;j<i;j++){
            int kj = (int)codes_lds[rib*13 + j];
            const float* qp = cbooks + (size_t)(j*1024+kj)*8;
            float4 q0 = *(const float4*)(qp);
            float4 q1 = *(const float4*)(qp+4);
            float qa[8] = {q0.x,q0.y,q0.z,q0.w,q1.x,q1.y,q1.z,q1.w};
            const float* M = ws + WS_M + (j*9+i)*64;
            #pragma unroll
            for (int a=0;a<8;a++){
                #pragma unroll
                for (int b=0;b<8;b++) ze[b] = fmaf(-qa[a], M[a*8+b], ze[b]);
            }
        }
        float ssq = 0.f;
        #pragma unroll
        for (int c=0;c<8;c++) ssq = fmaf(ze[c],ze[c],ssq);
        float den = fmaxf(sqrtf(ssq), 1e-12f);
        float rden = 1.0f/den;
        float zen[8];
        #pragma unroll
        for (int c=0;c<8;c++) zen[c] = ze[c]*rden;
        if (ah == 0){
            float4 n0 = {zen[0],zen[1],zen[2],zen[3]};
            float4 n1 = {zen[4],zen[5],zen[6],zen[7]};
            *(float4*)(zen_w + rowhalf*12)     = n0;
            *(float4*)(zen_w + rowhalf*12 + 4) = n1;
        } else {
            float4 z0 = {ze[0],ze[1],ze[2],ze[3]};
            float4 z1 = {ze[4],ze[5],ze[6],ze[7]};
            *(float4*)(lat)   = z0;
            *(float4*)(lat+4) = z1;
        }

        // ---- Phase B: wave scans its 32 rows; lane checks its 16 codes ----
        int ksave = 0;
        #pragma unroll 2
        for (int rr=0; rr<32; rr++){
            float4 zv0 = *(const float4*)(zen_w + rr*12);
            float4 zv1 = *(const float4*)(zen_w + rr*12 + 4);
            float z[8] = {zv0.x,zv0.y,zv0.z,zv0.w,zv1.x,zv1.y,zv1.z,zv1.w};
            float bv = -3.0e38f; int rel = 0;
            #pragma unroll
            for (int q=0;q<4;q++){
                float d0 = hs4[q].x, d1 = hs4[q].y, d2 = hs4[q].z, d3 = hs4[q].w;
                #pragma unroll
                for (int c=0;c<8;c++){
                    d0 = fmaf(z[c], cbr[q][c].x, d0);
                    d1 = fmaf(z[c], cbr[q][c].y, d1);
                    d2 = fmaf(z[c], cbr[q][c].z, d2);
                    d3 = fmaf(z[c], cbr[q][c].w, d3);
                }
                bool c0 = d0 > bv; rel = c0 ? (q*4+0) : rel; bv = c0 ? d0 : bv;
                bool c1 = d1 > bv; rel = c1 ? (q*4+1) : rel; bv = c1 ? d1 : bv;
                bool c2 = d2 > bv; rel = c2 ? (q*4+2) : rel; bv = c2 ? d2 : bv;
                bool c3 = d3 > bv; rel = c3 ? (q*4+3) : rel; bv = c3 ? d3 : bv;
            }
            int kfull = kb + rel;
            float wm = bv;
            #pragma unroll
            for (int off=1; off<64; off<<=1) wm = fmaxf(wm, __shfl_xor(wm, off, 64));
            unsigned long long msk = __ballot(bv == wm);
            int ln = __ffsll((long long)msk) - 1;    // lowest lane with max = lowest k
            int kwin = __shfl(kfull, ln, 64);
            ksave = (rowhalf == rr) ? kwin : ksave;
        }

        // ---- epilogue: pair splits loss (ah=0, has ze in regs) and writes (ah=1) ----
        if (ah == 0){
            const float* qp = cbooks + (size_t)(i*1024+ksave)*8;
            float4 q0 = *(const float4*)(qp);
            float4 q1 = *(const float4*)(qp+4);
            float e0 = ze[0]-q0.x, e1 = ze[1]-q0.y, e2 = ze[2]-q0.z, e3 = ze[3]-q0.w;
            float e4 = ze[4]-q1.x, e5 = ze[5]-q1.y, e6 = ze[6]-q1.z, e7 = ze[7]-q1.w;
            lacc = fmaf(e0,e0,lacc); lacc = fmaf(e1,e1,lacc);
            lacc = fmaf(e2,e2,lacc); lacc = fmaf(e3,e3,lacc);
            lacc = fmaf(e4,e4,lacc); lacc = fmaf(e5,e5,lacc);
            lacc = fmaf(e6,e6,lacc); lacc = fmaf(e7,e7,lacc);
        } else {
            out[OUT_CODES + (size_t)row*9 + i] = (float)ksave;
            codes_lds[rib*13 + i] = (float)ksave;
        }
    }

    // ---- loss reduction: one atomic per block ----
    #pragma unroll
    for (int off=1; off<64; off<<=1) lacc += __shfl_xor(lacc, off, 64);
    if ((tid & 63)==0) warr[tid>>6] = lacc;
    __syncthreads();
    if (tid==0){
        double bs = (double)warr[0]+(double)warr[1]+(double)warr[2]+(double)warr[3];
        atomicAdd((double*)&ws[WS_LOSS], bs);
    }
}

// ---------------- gemm_out: z_q = Q @ W_out_all + sum_out_b ----------------
__global__ __launch_bounds__(256) void gemm_out(const float* __restrict__ cbooks,
    const float* __restrict__ ws, float* __restrict__ out)
{
    __shared__ float QLT[72*140];   // word = k*140 + row + (row>>5)*4
    __shared__ float Ws[72*140];    // word = k*140 + col + (col>>3)*4
    int tid = threadIdx.x;
    int rowbase = blockIdx.x*128;
    if (tid < 128){
        int row = rowbase + tid;
        int rsw = tid + (tid>>5)*4;
        for (int j=0;j<9;j++){
            int kj = (int)out[OUT_CODES + (size_t)row*9 + j];
            const float* qp = cbooks + (size_t)(j*1024+kj)*8;
            float4 q0 = *(const float4*)qp;
            float4 q1 = *(const float4*)(qp+4);
            QLT[(j*8+0)*140 + rsw] = q0.x;
            QLT[(j*8+1)*140 + rsw] = q0.y;
            QLT[(j*8+2)*140 + rsw] = q0.z;
            QLT[(j*8+3)*140 + rsw] = q0.w;
            QLT[(j*8+4)*140 + rsw] = q1.x;
            QLT[(j*8+5)*140 + rsw] = q1.y;
            QLT[(j*8+6)*140 + rsw] = q1.z;
            QLT[(j*8+7)*140 + rsw] = q1.w;
        }
    }
    int tc = tid & 15, tr = tid >> 4;    // rows tr*8..+7, cols tc*8..+7 per chunk
    int aoff = tr*8 + (tr>>2)*4;
    int boff = tc*8 + (tc>>2)*4;
    for (int cc=0; cc<4; cc++){
        __syncthreads();
        #pragma unroll
        for (int p=0;p<9;p++){
            int idx = p*256 + tid;
            int jr = idx >> 5; int cq = idx & 31;
            float4 wv = *(const float4*)(ws + WS_WOUT + jr*512 + cc*128 + cq*4);
            *(float4*)(Ws + jr*140 + cq*4 + (cq>>3)*4) = wv;
        }
        __syncthreads();
        float acc[8][8];
        #pragma unroll
        for (int r=0;r<8;r++){
            #pragma unroll
            for (int c=0;c<8;c++) acc[r][c]=0.f;
        }
        #pragma unroll 2
        for (int k=0;k<72;k++){
            float4 a0 = *(const float4*)(QLT + k*140 + aoff);
            float4 a1 = *(const float4*)(QLT + k*140 + aoff + 4);
            float4 b0 = *(const float4*)(Ws + k*140 + boff);
            float4 b1 = *(const float4*)(Ws + k*140 + boff + 4);
            float av[8] = {a0.x,a0.y,a0.z,a0.w,a1.x,a1.y,a1.z,a1.w};
            float bw[8] = {b0.x,b0.y,b0.z,b0.w,b1.x,b1.y,b1.z,b1.w};
            #pragma unroll
            for (int r=0;r<8;r++){
                #pragma unroll
                for (int c=0;c<8;c++) acc[r][c] = fmaf(av[r], bw[c], acc[r][c]);
            }
        }
        float4 s0 = *(const float4*)(ws + WS_SOB + cc*128 + tc*8);
        float4 s1 = *(const float4*)(ws + WS_SOB + cc*128 + tc*8 + 4);
        #pragma unroll
        for (int r=0;r<8;r++){
            int row = rowbase + tr*8 + r;
            float4 o0 = {acc[r][0]+s0.x, acc[r][1]+s0.y, acc[r][2]+s0.z, acc[r][3]+s0.w};
            float4 o1 = {acc[r][4]+s1.x, acc[r][5]+s1.y, acc[r][6]+s1.z, acc[r][7]+s1.w};
            *(float4*)(out + (size_t)row*512 + cc*128 + tc*8)     = o0;
            *(float4*)(out + (size_t)row*512 + cc*128 + tc*8 + 4) = o1;
        }
    }
    if (blockIdx.x==0 && tid==0){
        double L = *(const double*)(ws + WS_LOSS);
        float lv = (float)(L * (1.0/524288.0));   // / (B*T*d)
        out[OUT_CLOSS]  = lv;
        out[OUT_CBLOSS] = lv;
    }
}

extern "C" void kernel_launch(void* const* d_in, const int* in_sizes, int n_in,
                              void* d_out, int out_size, void* d_ws, size_t ws_size,
                              hipStream_t stream) {
    const float* z     = (const float*)d_in[0];
    const float* in_v  = (const float*)d_in[1];
    const float* in_g  = (const float*)d_in[2];
    const float* in_b  = (const float*)d_in[3];
    const float* out_v = (const float*)d_in[4];
    const float* out_g = (const float*)d_in[5];
    const float* out_b = (const float*)d_in[6];
    const float* cb    = (const float*)d_in[7];
    float* out = (float*)d_out;
    float* ws  = (float*)d_ws;

    prep1<<<75, 256, 0, stream>>>(in_v, in_g, out_v, out_g, out_b, cb, ws);
    prep2<<<165, 256, 0, stream>>>(out_b, ws);
    gemm_in<<<512, 256, 0, stream>>>(z, in_b, ws, out);
    step_all<<<512, 256, 0, stream>>>(cb, ws, out);
    gemm_out<<<512, 256, 0, stream>>>(cb, ws, out);
}

// Round 4
// 596.736 us; speedup vs baseline: 1.1348x; 1.0033x over previous
//
#include <hip/hip_runtime.h>
#include <math.h>

// Problem constants: B=16, T=4096, D=512, N=9, K=1024, d=8
#define ROWS   65536

// ---- workspace float offsets ----
#define WS_WPAD 0          // W_in_all padded [512][96]: col cc=8i+c at (cc/9)*12+cc%9
#define WS_WOUT 49152      // W_out_all [72][512], row jr = 8j+a
#define WS_CBT  86016      // normalized codebooks transposed [9][8][1024]
#define WS_SC   159744     // sum(cb_n^2) [9][1024]
#define WS_M    168960     // M[j][i][a*8+b] = sum_t Wout[j][a][t]*Win[i][t][b]
#define WS_CACC 174144     // [9][8]: sum_{j<i} out_b_j @ W_in_i
#define WS_SOB  174216     // [512]: sum_j out_b_j
#define WS_LOSS 174728     // double accumulator (8B aligned)

// ---- output float offsets ----
#define OUT_CODES 33554432
#define OUT_LAT   34144256
#define OUT_CLOSS 38862848
#define OUT_CBLOSS 38862849

// ---- fused-kernel LDS float offsets (total 19880 floats = 79.5 KB) ----
#define SM_AST   0        // [32][132] gemm_in A-tile (phase 1)
#define SM_BS    4224     // [32][96]  gemm_in B-tile (phase 1)
#define SM_P     0        // [128][72] latents pre-stage (phase 2; overlaps AsT/Bs)
#define SM_QLT   0        // [72][128] Q transposed (phase 3; overlaps P)
#define SM_REG2  9216     // zen [4][32][12] (phase 2) / Ws [72][132] skewed (phase 3)
#define SM_CODES 18720    // [128][9]
#define SM_WARR  19872    // [8]

__device__ __forceinline__ int pcol(int cc){ return (cc/9)*12 + (cc%9); }

// ---------------- prep1: weight-norm + codebook normalize ----------------
__global__ __launch_bounds__(256) void prep1(const float* __restrict__ in_v,
    const float* __restrict__ in_g, const float* __restrict__ out_v,
    const float* __restrict__ out_g, const float* __restrict__ out_b,
    const float* __restrict__ cb, float* __restrict__ ws)
{
    int t = blockIdx.x*256 + threadIdx.x;
    if (t < 9216) {
        int i = t >> 10, k = t & 1023;
        const float* p = cb + (i*1024 + k)*8;
        float v[8]; float ssq = 0.f;
        #pragma unroll
        for (int c=0;c<8;c++){ v[c]=p[c]; ssq = fmaf(v[c],v[c],ssq); }
        float den = fmaxf(sqrtf(ssq), 1e-12f);
        float sc = 0.f;
        #pragma unroll
        for (int c=0;c<8;c++){ float cn = v[c]/den; ws[WS_CBT + (i*8+c)*1024 + k] = cn; sc = fmaf(cn,cn,sc); }
        ws[WS_SC + i*1024 + k] = sc;
    } else if (t < 13824) {
        int r = t - 9216; int j = r >> 9, tt = r & 511;
        float v[8]; float ssq = 0.f;
        #pragma unroll
        for (int a=0;a<8;a++){ v[a]=out_v[(j*8+a)*512+tt]; ssq=fmaf(v[a],v[a],ssq); }
        float den = fmaxf(sqrtf(ssq), 1e-12f);
        float g = out_g[j*512+tt];
        #pragma unroll
        for (int a=0;a<8;a++) ws[WS_WOUT + (j*8+a)*512 + tt] = g*v[a]/den;
    } else if (t < 18432) {
        int r = t - 13824;
        int w = r >> 6, l = r & 63;
        int i = w >> 3, c = w & 7;
        float v[8]; float ssq = 0.f;
        #pragma unroll
        for (int u=0;u<8;u++){ v[u] = in_v[(i*512 + l*8+u)*8 + c]; ssq = fmaf(v[u],v[u],ssq); }
        #pragma unroll
        for (int off=1; off<64; off<<=1) ssq += __shfl_xor(ssq, off, 64);
        float den = fmaxf(sqrtf(ssq), 1e-12f);
        float g = in_g[i*8+c];
        int pc = pcol(i*8+c);
        #pragma unroll
        for (int u=0;u<8;u++) ws[WS_WPAD + (l*8+u)*96 + pc] = g*v[u]/den;
    } else if (t < 18944) {
        int tt = t - 18432;
        float s = 0.f;
        for (int j=0;j<9;j++) s += out_b[j*512+tt];
        ws[WS_SOB + tt] = s;
    } else if (t == 18944) {
        *(double*)&ws[WS_LOSS] = 0.0;
    }
}

// ---------------- prep2: cross-term tables M and Cacc ----------------
__global__ __launch_bounds__(256) void prep2(const float* __restrict__ out_b,
                                             float* __restrict__ ws)
{
    int g = blockIdx.x*256 + threadIdx.x;
    if (g < 41472) {
        int oi = g >> 3, part = g & 7;
        int j = oi / 576; int rem = oi % 576; int i = rem >> 6; int ab = rem & 63;
        int a = ab >> 3, b = ab & 7;
        int pc = pcol(i*8+b);
        const float* wo = ws + WS_WOUT + (j*8+a)*512 + part*64;
        const float* wp = ws + WS_WPAD + (part*64)*96 + pc;
        float s = 0.f;
        #pragma unroll
        for (int u=0; u<16; u++) {
            float4 w4 = *(const float4*)(wo + u*4);
            s = fmaf(w4.x, wp[(u*4+0)*96], s);
            s = fmaf(w4.y, wp[(u*4+1)*96], s);
            s = fmaf(w4.z, wp[(u*4+2)*96], s);
            s = fmaf(w4.w, wp[(u*4+3)*96], s);
        }
        #pragma unroll
        for (int off=1; off<8; off<<=1) s += __shfl_xor(s, off, 64);
        if (part == 0) ws[WS_M + oi] = s;   // oi == (j*9+i)*64 + ab
    } else if (g < 42048) {
        int r = g - 41472;
        int oi = r >> 3, part = r & 7;
        int i = oi >> 3, b = oi & 7;
        int pc = pcol(i*8+b);
        float s = 0.f;
        for (int u=0; u<64; u++) {
            int tt = part*64 + u;
            float bb = 0.f;
            for (int j=0;j<i;j++) bb += out_b[j*512+tt];
            s = fmaf(bb, ws[WS_WPAD + tt*96+pc], s);
        }
        #pragma unroll
        for (int off=1; off<8; off<<=1) s += __shfl_xor(s, off, 64);
        if (part == 0) ws[WS_CACC + oi] = s;
    }
}

// ---------------- fused_all: gemm_in -> 9 stages -> gemm_out, one block = 128 rows ----
__global__ __launch_bounds__(256, 2) void fused_all(
    const float* __restrict__ z, const float* __restrict__ in_b,
    const float* __restrict__ cbooks, float* __restrict__ ws, float* __restrict__ out)
{
    __shared__ __align__(16) float smem[19880];
    int tid = threadIdx.x;
    int brow = blockIdx.x * 128;

    // ============ phase 1: gemm_in (identical compute) -> P in LDS ============
    {
        float* AsT = smem + SM_AST;   // [k][row], stride 132
        float* Bs  = smem + SM_BS;    // [k][96]
        int tr = tid & 31, tc = tid >> 5;
        float acc[4][9];
        #pragma unroll
        for (int r=0;r<4;r++){
            #pragma unroll
            for(int c=0;c<9;c++) acc[r][c]=0.f;
        }
        int kq = tid & 7, rr = tid >> 3;
        for (int kk=0; kk<16; kk++) {
            #pragma unroll
            for (int p=0;p<4;p++){
                int row = rr + p*32;
                float4 a = *(const float4*)(z + (size_t)(brow+row)*512 + kk*32 + kq*4);
                AsT[(kq*4+0)*132 + row] = a.x;
                AsT[(kq*4+1)*132 + row] = a.y;
                AsT[(kq*4+2)*132 + row] = a.z;
                AsT[(kq*4+3)*132 + row] = a.w;
            }
            #pragma unroll
            for (int p=0;p<3;p++){
                int idx = p*256 + tid;
                *(float4*)(Bs + idx*4) = *(const float4*)(ws + WS_WPAD + kk*32*96 + idx*4);
            }
            __syncthreads();
            #pragma unroll 4
            for (int k=0;k<32;k++){
                float4 a  = *(const float4*)(AsT + k*132 + tr*4);
                float4 b0 = *(const float4*)(Bs + k*96 + tc*12);
                float4 b1 = *(const float4*)(Bs + k*96 + tc*12 + 4);
                float  b8 = Bs[k*96 + tc*12 + 8];
                float av[4] = {a.x,a.y,a.z,a.w};
                float bv[9] = {b0.x,b0.y,b0.z,b0.w,b1.x,b1.y,b1.z,b1.w,b8};
                #pragma unroll
                for (int r=0;r<4;r++){
                    #pragma unroll
                    for (int c=0;c<9;c++) acc[r][c] = fmaf(av[r], bv[c], acc[r][c]);
                }
            }
            __syncthreads();
        }
        // staging dead -> write P (overlaps AsT region)
        float* P = smem + SM_P;
        #pragma unroll
        for (int c=0;c<9;c++){
            int cc = tc*9+c;
            float bias = in_b[cc];
            #pragma unroll
            for (int r=0;r<4;r++){
                int rl = tr*4 + r;
                P[rl*72 + cc] = acc[r][c] + bias;
            }
        }
        __syncthreads();
    }

    // ============ phase 2: 9 quantizer stages (wave-autonomous) ============
    int w  = tid >> 6;
    int l  = tid & 63;
    int rowhalf = l >> 1;
    int ah = l & 1;
    int wrow = brow + w*32;
    int kb = l*16;
    float* P = smem + SM_P;
    float* zen_w = smem + SM_REG2 + w*384;
    float* codes_lds = smem + SM_CODES;   // [row][9]

    float lacc = 0.f;
    float4 cbr[4][8];
    float4 hs4[4];

    #pragma unroll 1
    for (int i=0; i<9; i++){
        // reload this lane's 16 codes + prescaled -0.5*sc (L2/L1-resident)
        #pragma unroll
        for (int q=0;q<4;q++){
            #pragma unroll
            for (int c=0;c<8;c++)
                cbr[q][c] = *(const float4*)(ws + WS_CBT + i*8192 + c*1024 + kb + q*4);
            float4 s = *(const float4*)(ws + WS_SC + i*1024 + kb + q*4);
            hs4[q].x = s.x * -0.5f; hs4[q].y = s.y * -0.5f;
            hs4[q].z = s.z * -0.5f; hs4[q].w = s.w * -0.5f;
        }

        // ---- Phase A: ze for own row (pair-redundant, exact op order) ----
        int row = wrow + rowhalf;
        int rib = w*32 + rowhalf;
        float* lat = out + OUT_LAT + (size_t)row*72 + i*8;
        float4 p0 = *(const float4*)(P + rib*72 + i*8);
        float4 p1 = *(const float4*)(P + rib*72 + i*8 + 4);
        float ze[8] = {p0.x,p0.y,p0.z,p0.w,p1.x,p1.y,p1.z,p1.w};
        #pragma unroll
        for (int b=0;b<8;b++) ze[b] -= ws[WS_CACC + i*8 + b];
        #pragma unroll 1
        for (int j=0;j<i;j++){
            int kj = (int)codes_lds[rib*9 + j];
            const float* qp = cbooks + (size_t)(j*1024+kj)*8;
            float4 q0 = *(const float4*)(qp);
            float4 q1 = *(const float4*)(qp+4);
            float qa[8] = {q0.x,q0.y,q0.z,q0.w,q1.x,q1.y,q1.z,q1.w};
            const float* M = ws + WS_M + (j*9+i)*64;
            #pragma unroll
            for (int a=0;a<8;a++){
                #pragma unroll
                for (int b=0;b<8;b++) ze[b] = fmaf(-qa[a], M[a*8+b], ze[b]);
            }
        }
        float ssq = 0.f;
        #pragma unroll
        for (int c=0;c<8;c++) ssq = fmaf(ze[c],ze[c],ssq);
        float den = fmaxf(sqrtf(ssq), 1e-12f);
        float rden = 1.0f/den;
        float zen[8];
        #pragma unroll
        for (int c=0;c<8;c++) zen[c] = ze[c]*rden;
        if (ah == 0){
            float4 n0 = {zen[0],zen[1],zen[2],zen[3]};
            float4 n1 = {zen[4],zen[5],zen[6],zen[7]};
            *(float4*)(zen_w + rowhalf*12)     = n0;
            *(float4*)(zen_w + rowhalf*12 + 4) = n1;
        } else {
            float4 z0 = {ze[0],ze[1],ze[2],ze[3]};
            float4 z1 = {ze[4],ze[5],ze[6],ze[7]};
            *(float4*)(lat)   = z0;
            *(float4*)(lat+4) = z1;
        }

        // ---- Phase B: wave scans its 32 rows; lane checks its 16 codes ----
        int ksave = 0;
        #pragma unroll 2
        for (int rr=0; rr<32; rr++){
            float4 zv0 = *(const float4*)(zen_w + rr*12);
            float4 zv1 = *(const float4*)(zen_w + rr*12 + 4);
            float zr[8] = {zv0.x,zv0.y,zv0.z,zv0.w,zv1.x,zv1.y,zv1.z,zv1.w};
            float bv = -3.0e38f; int rel = 0;
            #pragma unroll
            for (int q=0;q<4;q++){
                float d0 = hs4[q].x, d1 = hs4[q].y, d2 = hs4[q].z, d3 = hs4[q].w;
                #pragma unroll
                for (int c=0;c<8;c++){
                    d0 = fmaf(zr[c], cbr[q][c].x, d0);
                    d1 = fmaf(zr[c], cbr[q][c].y, d1);
                    d2 = fmaf(zr[c], cbr[q][c].z, d2);
                    d3 = fmaf(zr[c], cbr[q][c].w, d3);
                }
                bool c0 = d0 > bv; rel = c0 ? (q*4+0) : rel; bv = c0 ? d0 : bv;
                bool c1 = d1 > bv; rel = c1 ? (q*4+1) : rel; bv = c1 ? d1 : bv;
                bool c2 = d2 > bv; rel = c2 ? (q*4+2) : rel; bv = c2 ? d2 : bv;
                bool c3 = d3 > bv; rel = c3 ? (q*4+3) : rel; bv = c3 ? d3 : bv;
            }
            int kfull = kb + rel;
            float wm = bv;
            #pragma unroll
            for (int off=1; off<64; off<<=1) wm = fmaxf(wm, __shfl_xor(wm, off, 64));
            unsigned long long msk = __ballot(bv == wm);
            int ln = __ffsll((long long)msk) - 1;    // lowest lane with max = lowest k
            int kwin = __shfl(kfull, ln, 64);
            ksave = (rowhalf == rr) ? kwin : ksave;
        }

        // ---- epilogue: pair splits loss (ah=0) and writes (ah=1) ----
        if (ah == 0){
            const float* qp = cbooks + (size_t)(i*1024+ksave)*8;
            float4 q0 = *(const float4*)(qp);
            float4 q1 = *(const float4*)(qp+4);
            float e0 = ze[0]-q0.x, e1 = ze[1]-q0.y, e2 = ze[2]-q0.z, e3 = ze[3]-q0.w;
            float e4 = ze[4]-q1.x, e5 = ze[5]-q1.y, e6 = ze[6]-q1.z, e7 = ze[7]-q1.w;
            lacc = fmaf(e0,e0,lacc); lacc = fmaf(e1,e1,lacc);
            lacc = fmaf(e2,e2,lacc); lacc = fmaf(e3,e3,lacc);
            lacc = fmaf(e4,e4,lacc); lacc = fmaf(e5,e5,lacc);
            lacc = fmaf(e6,e6,lacc); lacc = fmaf(e7,e7,lacc);
        } else {
            out[OUT_CODES + (size_t)row*9 + i] = (float)ksave;
            codes_lds[rib*9 + i] = (float)ksave;
        }
    }

    // ---- loss reduction: one atomic per block ----
    {
        float* warr = smem + SM_WARR;
        #pragma unroll
        for (int off=1; off<64; off<<=1) lacc += __shfl_xor(lacc, off, 64);
        if ((tid & 63)==0) warr[w] = lacc;
        __syncthreads();
        if (tid==0){
            double bs = (double)warr[0]+(double)warr[1]+(double)warr[2]+(double)warr[3];
            atomicAdd((double*)&ws[WS_LOSS], bs);
        }
    }

    // ============ phase 3: gemm_out (identical compute), Q from codes_lds ============
    __syncthreads();   // P dead; QLT/Ws regions free
    {
        float* QLT = smem + SM_QLT;   // [k=72][row=128]
        float* Ws  = smem + SM_REG2;  // [72][132], word w -> w + (w>>6)*4
        if (tid < 128){
            for (int j=0;j<9;j++){
                int kj = (int)codes_lds[tid*9 + j];
                const float* qp = cbooks + (size_t)(j*1024+kj)*8;
                float4 q0 = *(const float4*)qp;
                float4 q1 = *(const float4*)(qp+4);
                QLT[(j*8+0)*128 + tid] = q0.x;
                QLT[(j*8+1)*128 + tid] = q0.y;
                QLT[(j*8+2)*128 + tid] = q0.z;
                QLT[(j*8+3)*128 + tid] = q0.w;
                QLT[(j*8+4)*128 + tid] = q1.x;
                QLT[(j*8+5)*128 + tid] = q1.y;
                QLT[(j*8+6)*128 + tid] = q1.z;
                QLT[(j*8+7)*128 + tid] = q1.w;
            }
        }
        int tc = tid & 15, tr = tid >> 4;    // rows tr*8..+7, cols tc*8..+7 per chunk
        int aoff = tr*8;
        int boff = tc*8 + (tc>>3)*4;
        for (int cc=0; cc<4; cc++){
            __syncthreads();
            #pragma unroll
            for (int p=0;p<9;p++){
                int idx = p*256 + tid;
                int jr = idx >> 5; int cq = idx & 31;
                float4 wv = *(const float4*)(ws + WS_WOUT + jr*512 + cc*128 + cq*4);
                *(float4*)(Ws + jr*132 + cq*4 + (cq>>4)*4) = wv;
            }
            __syncthreads();
            float acc[8][8];
            #pragma unroll
            for (int r=0;r<8;r++){
                #pragma unroll
                for (int c=0;c<8;c++) acc[r][c]=0.f;
            }
            #pragma unroll 2
            for (int k=0;k<72;k++){
                float4 a0 = *(const float4*)(QLT + k*128 + aoff);
                float4 a1 = *(const float4*)(QLT + k*128 + aoff + 4);
                float4 b0 = *(const float4*)(Ws + k*132 + boff);
                float4 b1 = *(const float4*)(Ws + k*132 + boff + 4);
                float av[8] = {a0.x,a0.y,a0.z,a0.w,a1.x,a1.y,a1.z,a1.w};
                float bw[8] = {b0.x,b0.y,b0.z,b0.w,b1.x,b1.y,b1.z,b1.w};
                #pragma unroll
                for (int r=0;r<8;r++){
                    #pragma unroll
                    for (int c=0;c<8;c++) acc[r][c] = fmaf(av[r], bw[c], acc[r][c]);
                }
            }
            float4 s0 = *(const float4*)(ws + WS_SOB + cc*128 + tc*8);
            float4 s1 = *(const float4*)(ws + WS_SOB + cc*128 + tc*8 + 4);
            #pragma unroll
            for (int r=0;r<8;r++){
                int row = brow + tr*8 + r;
                float4 o0 = {acc[r][0]+s0.x, acc[r][1]+s0.y, acc[r][2]+s0.z, acc[r][3]+s0.w};
                float4 o1 = {acc[r][4]+s1.x, acc[r][5]+s1.y, acc[r][6]+s1.z, acc[r][7]+s1.w};
                *(float4*)(out + (size_t)row*512 + cc*128 + tc*8)     = o0;
                *(float4*)(out + (size_t)row*512 + cc*128 + tc*8 + 4) = o1;
            }
        }
    }
}

// ---------------- finalize: loss scalars ----------------
__global__ void finalize(const float* __restrict__ ws, float* __restrict__ out)
{
    if (threadIdx.x == 0){
        double L = *(const double*)(ws + WS_LOSS);
        float lv = (float)(L * (1.0/524288.0));   // / (B*T*d)
        out[OUT_CLOSS]  = lv;
        out[OUT_CBLOSS] = lv;
    }
}

extern "C" void kernel_launch(void* const* d_in, const int* in_sizes, int n_in,
                              void* d_out, int out_size, void* d_ws, size_t ws_size,
                              hipStream_t stream) {
    const float* z     = (const float*)d_in[0];
    const float* in_v  = (const float*)d_in[1];
    const float* in_g  = (const float*)d_in[2];
    const float* in_b  = (const float*)d_in[3];
    const float* out_v = (const float*)d_in[4];
    const float* out_g = (const float*)d_in[5];
    const float* out_b = (const float*)d_in[6];
    const float* cb    = (const float*)d_in[7];
    float* out = (float*)d_out;
    float* ws  = (float*)d_ws;

    prep1<<<75, 256, 0, stream>>>(in_v, in_g, out_v, out_g, out_b, cb, ws);
    prep2<<<165, 256, 0, stream>>>(out_b, ws);
    fused_all<<<512, 256, 0, stream>>>(z, in_b, cb, ws, out);
    finalize<<<1, 64, 0, stream>>>(ws, out);
}